// Round 14
// baseline (325.996 us; speedup 1.0000x reference)
//
#include <hip/hip_runtime.h>
#include <math.h>

// SeesawLoss, one-hot specialization, two-pass:
//   Pass 1 (label_kernel): flat float4 scan of targets -> labels[n].
//   Pass 2 (seesaw_row_kernel): wave-per-row, ALL-float4 loads.
//     Rows are 4920B (8-mod-16 base on odd rows): gfx950 global dwordx4 needs
//     only dword alignment, so 8-aligned float4 loads are HW-legal. Row tail
//     (elems 1228..1229) is an exact float2 -> no overread on any row.
//     Invalid lane components get -INF logits => exp()=0 => dot self-masks.
//   loss[n] = log(denom+eps) - (l[n,li] - m),
//   denom = sum_j s[li,j]e_j - s[li,li]e_li + e_li,  e = exp(l - m)
// History: r5 117us latency-bound (VGPR=28, 1KB in flight); r9 two-pass put
// seesaw <92us (below harness fills). This round: float2->float4, 21->13
// loads/wave, 16B/lane coalescing sweet spot.

constexpr int N_ROWS = 32768;
constexpr int C_CLS  = 1230;
constexpr int C4     = C_CLS / 4;        // 307 full float4 per row (+2-elem tail)
constexpr int T2     = C_CLS / 2 - 1;    // 614: float2 index of the row tail
constexpr int BLK    = 256;
constexpr int WPB    = BLK / 64;         // 4 rows per block
constexpr unsigned TOT  = (unsigned)N_ROWS * (unsigned)C_CLS;  // 40,304,640
constexpr unsigned TOT4 = TOT / 4;                             // 10,076,160
constexpr float EPS_F = 1e-6f;

// ---- Pass 1: extract labels from one-hot targets (flat float4 stream) ------
__global__ __launch_bounds__(BLK) void label_kernel(
    const float* __restrict__ targets, int* __restrict__ labels)
{
    const float4* t4 = reinterpret_cast<const float4*>(targets);
    const unsigned stride = gridDim.x * BLK;
    for (unsigned i = blockIdx.x * BLK + threadIdx.x; i < TOT4; i += stride) {
        const float4 v = t4[i];
        if (v.x > 0.5f || v.y > 0.5f || v.z > 0.5f || v.w > 0.5f) {  // rare (1/308)
            const unsigned g = i * 4u;
            #pragma unroll
            for (int e = 0; e < 4; ++e) {
                const float val = (e == 0) ? v.x : (e == 1) ? v.y : (e == 2) ? v.z : v.w;
                if (val > 0.5f) {
                    const unsigned gg = g + (unsigned)e;
                    const unsigned n  = gg / (unsigned)C_CLS;   // magic-mul div
                    const unsigned c  = gg - n * (unsigned)C_CLS;
                    labels[n] = (int)c;
                }
            }
        }
    }
}

// ---- Pass 2: per-row loss, wave-per-row, float4 deep load batch ------------
__global__ __launch_bounds__(BLK) void seesaw_row_kernel(
    const float* __restrict__ logits,
    const float* __restrict__ s,
    const int*   __restrict__ labels,
    float* __restrict__ row_loss)
{
    const int t    = threadIdx.x;
    const int lane = t & 63;
    const int wv   = t >> 6;
    const int n    = blockIdx.x * WPB + wv;

    // 1) label (longest chain: s-row base depends on it)
    const int li = __builtin_amdgcn_readfirstlane(labels[n]);

    const float* lrow = logits + (size_t)n * C_CLS;
    const float* srow = s + (size_t)li * C_CLS;
    const float4* lrow4 = reinterpret_cast<const float4*>(lrow);  // may be 8-mod-16: HW-legal
    const float2* lrow2 = reinterpret_cast<const float2*>(lrow);
    const float4* srow4 = reinterpret_cast<const float4*>(srow);
    const float2* srow2 = reinterpret_cast<const float2*>(srow);

    // 2) logits row: iters 0..3 fully valid (idx4<=255), iter 4 partial
    float4 l[5];
    #pragma unroll
    for (int it = 0; it < 5; ++it) {
        const int idx4 = lane + it * 64;
        if (idx4 < C4) {
            l[it] = lrow4[idx4];
        } else if (idx4 == C4) {                 // exact tail: elems 1228,1229
            const float2 tl = lrow2[T2];
            l[it] = make_float4(tl.x, tl.y, -INFINITY, -INFINITY);
        } else {
            l[it] = make_float4(-INFINITY, -INFINITY, -INFINITY, -INFINITY);
        }
    }

    // 3) s row gather (L2/L3-resident), same shape
    float4 sv[5];
    #pragma unroll
    for (int it = 0; it < 5; ++it) {
        const int idx4 = lane + it * 64;
        if (idx4 < C4) {
            sv[it] = srow4[idx4];
        } else if (idx4 == C4) {
            const float2 ts = srow2[T2];
            sv[it] = make_float4(ts.x, ts.y, 0.0f, 0.0f);
        } else {
            sv[it] = make_float4(0.0f, 0.0f, 0.0f, 0.0f);
        }
    }
    const float lval = lrow[li];   // broadcast scalar loads
    const float sii  = srow[li];   // == 1.0 by construction

    // 4) row max; -INF fills make invalid comps inert
    float lmax = -INFINITY;
    #pragma unroll
    for (int it = 0; it < 5; ++it)
        lmax = fmaxf(lmax, fmaxf(fmaxf(l[it].x, l[it].y), fmaxf(l[it].z, l[it].w)));
    #pragma unroll
    for (int off = 32; off > 0; off >>= 1)
        lmax = fmaxf(lmax, __shfl_xor(lmax, off));
    const float m = lmax;

    // 5) dot( s[li,:], exp(l - m) ): exp(-INF)=0 self-masks the tail
    float part = 0.0f;
    #pragma unroll
    for (int it = 0; it < 5; ++it) {
        part = fmaf(sv[it].x, __expf(l[it].x - m), part);
        part = fmaf(sv[it].y, __expf(l[it].y - m), part);
        part = fmaf(sv[it].z, __expf(l[it].z - m), part);
        part = fmaf(sv[it].w, __expf(l[it].w - m), part);
    }
    #pragma unroll
    for (int off = 32; off > 0; off >>= 1)
        part += __shfl_xor(part, off);

    if (lane == 0) {
        const float ei    = __expf(lval - m);
        const float denom = part - sii * ei + ei;
        row_loss[n] = __logf(denom + EPS_F) - (lval - m);
    }
}

// ---- Deterministic mean (double accum), one 1024-thread block --------------
__global__ __launch_bounds__(1024) void reduce_mean_kernel(
    const float* __restrict__ row_loss, float* __restrict__ out)
{
    const int t    = threadIdx.x;
    const int lane = t & 63;
    const int wv   = t >> 6;                    // 16 waves
    const float4* rl4 = reinterpret_cast<const float4*>(row_loss);
    constexpr int N4 = N_ROWS / 4;              // 8192
    double acc = 0.0;
    #pragma unroll 8
    for (int i = t; i < N4; i += 1024) {
        const float4 v = rl4[i];
        acc += (double)v.x + (double)v.y + (double)v.z + (double)v.w;
    }
    #pragma unroll
    for (int off = 32; off > 0; off >>= 1)
        acc += __shfl_down(acc, off);
    __shared__ double red[16];
    if (lane == 0) red[wv] = acc;
    __syncthreads();
    if (t == 0) {
        double tot = 0.0;
        #pragma unroll
        for (int w = 0; w < 16; ++w) tot += red[w];
        out[0] = (float)(tot / (double)N_ROWS);
    }
}

extern "C" void kernel_launch(void* const* d_in, const int* in_sizes, int n_in,
                              void* d_out, int out_size, void* d_ws, size_t ws_size,
                              hipStream_t stream) {
    const float* logits  = (const float*)d_in[0];   // [N, C]
    const float* targets = (const float*)d_in[1];   // [N, C] one-hot f32
    const float* s       = (const float*)d_in[2];   // [C, C]
    float* out = (float*)d_out;                     // scalar f32

    int*   labels   = (int*)d_ws;                           // 128 KiB
    float* row_loss = (float*)((char*)d_ws + N_ROWS * 4);   // 128 KiB

    label_kernel<<<2048, BLK, 0, stream>>>(targets, labels);
    seesaw_row_kernel<<<N_ROWS / WPB, BLK, 0, stream>>>(logits, s, labels, row_loss);
    reduce_mean_kernel<<<1, 1024, 0, stream>>>(row_loss, out);
}